// Round 2
// baseline (12279.877 us; speedup 1.0000x reference)
//
#include <hip/hip_runtime.h>
#include <hip/hip_bf16.h>
#include <stdint.h>

typedef float f32x4 __attribute__((ext_vector_type(4)));
typedef short bf16x8 __attribute__((ext_vector_type(8)));

#define LDW 1024
#define BATCH_SH 20  // 1<<20 elements per 1024x1024 matrix

__device__ __forceinline__ float b2f(__hip_bfloat16 h) { return __bfloat162float(h); }
__device__ __forceinline__ __hip_bfloat16 f2b(float f) { return __float2bfloat16(f); }

// ---------------- Frobenius norm (2-stage) ----------------
__global__ void k_partial(const float* __restrict__ xin, float* __restrict__ partials) {
  const int b = blockIdx.y, ch = blockIdx.x, t = threadIdx.x;
  const size_t base = ((size_t)b << BATCH_SH) + (size_t)ch * 16384;
  float s = 0.f;
#pragma unroll
  for (int i = 0; i < 16; ++i) {
    f32x4 v = *reinterpret_cast<const f32x4*>(xin + base + (size_t)(i * 256 + t) * 4);
    s += v[0] * v[0] + v[1] * v[1] + v[2] * v[2] + v[3] * v[3];
  }
#pragma unroll
  for (int off = 32; off; off >>= 1) s += __shfl_down(s, off);
  __shared__ float red[4];
  if ((t & 63) == 0) red[t >> 6] = s;
  __syncthreads();
  if (t == 0) partials[b * 64 + ch] = red[0] + red[1] + red[2] + red[3];
}

__global__ void k_scale(const float* __restrict__ partials, float* __restrict__ scales) {
  const int b = blockIdx.x, t = threadIdx.x;
  float s = partials[b * 64 + t];
#pragma unroll
  for (int off = 32; off; off >>= 1) s += __shfl_down(s, off);
  if (t == 0) scales[b] = 1.1f / sqrtf(s);
}

// ---------------- scale + split + transpose-split ----------------
__global__ void k_scalesplit(const float* __restrict__ xin, const float* __restrict__ scales,
                             float* __restrict__ X, __hip_bfloat16* __restrict__ Xh,
                             __hip_bfloat16* __restrict__ Xl, __hip_bfloat16* __restrict__ XTh,
                             __hip_bfloat16* __restrict__ XTl) {
  __shared__ float tile[64][65];
  const int b = blockIdx.z, tm = blockIdx.y, tn = blockIdx.x;
  const size_t boff = (size_t)b << BATCH_SH;
  const float s = scales[b];
  const int t = threadIdx.x, lr0 = t >> 6, lc = t & 63;
#pragma unroll
  for (int p = 0; p < 16; ++p) {
    const int lr = p * 4 + lr0;
    const size_t idx = boff + (size_t)(tm * 64 + lr) * LDW + tn * 64 + lc;
    const float v = xin[idx] * s;
    X[idx] = v;
    __hip_bfloat16 h = f2b(v);
    Xh[idx] = h;
    Xl[idx] = f2b(v - b2f(h));
    tile[lr][lc] = v;
  }
  __syncthreads();
#pragma unroll
  for (int p = 0; p < 16; ++p) {
    const int lr = p * 4 + lr0;
    const float v = tile[lc][lr];  // XT[tn*64+lr][tm*64+lc] = X[tm*64+lc][tn*64+lr]
    const size_t idx = boff + (size_t)(tn * 64 + lr) * LDW + tm * 64 + lc;
    __hip_bfloat16 h = f2b(v);
    XTh[idx] = h;
    XTl[idx] = f2b(v - b2f(h));
  }
}

// ---------------- split-bf16 GEMM: C = PA * PB^T over 3 K-segments ----------------
// PA, PB row-major [1024][1024] bf16 panels (K contiguous). Effective K = 3072.
// Register-staged LDS (2-barrier classic), self-consistent XOR chunk swizzle.
// MODE 0: oh/ol = hi/lo splits of C
// MODE 2: xn = c0*exf + c1*(exh+exl) + c2*C; of=xn; oh/ol=splits; oth/otl=transposed splits

template <int MODE>
__global__ __launch_bounds__(256) void k_gemm(
    const __hip_bfloat16* __restrict__ pa0, const __hip_bfloat16* __restrict__ pa1,
    const __hip_bfloat16* __restrict__ pa2, const __hip_bfloat16* __restrict__ pb0,
    const __hip_bfloat16* __restrict__ pb1, const __hip_bfloat16* __restrict__ pb2,
    __hip_bfloat16* __restrict__ oh, __hip_bfloat16* __restrict__ ol,
    __hip_bfloat16* __restrict__ oth, __hip_bfloat16* __restrict__ otl,
    float* of, const float* exf,
    const __hip_bfloat16* __restrict__ exh, const __hip_bfloat16* __restrict__ exl,
    const float* __restrict__ coef) {
  __shared__ __align__(16) char smem[32768];  // A 16KB + B 16KB, single buffer
  const int tid = threadIdx.x;
  const int w = tid >> 6, l = tid & 63;
  const int wr = w >> 1, wc = w & 1;
  const size_t boff = (size_t)blockIdx.y << BATCH_SH;
  const int tm = blockIdx.x >> 3, tn = blockIdx.x & 7;
  const int rowA = tm * 128, rowB = tn * 128;
  const int srow = l >> 3, gl = l & 7;

  f32x4 acc[4][4];
#pragma unroll
  for (int i = 0; i < 4; ++i)
#pragma unroll
    for (int j = 0; j < 4; ++j) acc[i][j] = (f32x4){0.f, 0.f, 0.f, 0.f};

  // LDS byte offsets of MFMA fragments (XOR chunk swizzle, matches write side below)
  int offA[2][4], offB[2][4];
#pragma unroll
  for (int kk = 0; kk < 2; ++kk) {
#pragma unroll
    for (int i = 0; i < 4; ++i) {
      const int g = kk * 4 + (l >> 4);
      const int rA = wr * 64 + i * 16 + (l & 15);
      offA[kk][i] = rA * 128 + ((g ^ (rA & 7)) << 4);
      const int rB = wc * 64 + i * 16 + (l & 15);
      offB[kk][i] = 16384 + rB * 128 + ((g ^ (rB & 7)) << 4);
    }
  }

  for (int s = 0; s < 48; ++s) {
    const int seg = s >> 4, k0 = (s & 15) << 6;
    const __hip_bfloat16* pa_ = seg == 0 ? pa0 : seg == 1 ? pa1 : pa2;
    const __hip_bfloat16* pb_ = seg == 0 ? pb0 : seg == 1 ? pb1 : pb2;
    bf16x8 va[4], vb[4];
#pragma unroll
    for (int it = 0; it < 4; ++it) {
      const int r = w * 32 + it * 8 + srow;
      va[it] = *reinterpret_cast<const bf16x8*>(pa_ + boff + (size_t)(rowA + r) * LDW + k0 + gl * 8);
      vb[it] = *reinterpret_cast<const bf16x8*>(pb_ + boff + (size_t)(rowB + r) * LDW + k0 + gl * 8);
    }
    __syncthreads();  // all waves done READING smem (previous step)
#pragma unroll
    for (int it = 0; it < 4; ++it) {
      const int r = w * 32 + it * 8 + srow;
      // chunk gl of row r goes to slot gl ^ (r&7); (r&7) == srow
      *reinterpret_cast<bf16x8*>(smem + r * 128 + ((gl ^ srow) << 4)) = va[it];
      *reinterpret_cast<bf16x8*>(smem + 16384 + r * 128 + ((gl ^ srow) << 4)) = vb[it];
    }
    __syncthreads();  // smem staged
#pragma unroll
    for (int kk = 0; kk < 2; ++kk) {
      bf16x8 av[4], bv[4];
#pragma unroll
      for (int i = 0; i < 4; ++i) av[i] = *reinterpret_cast<const bf16x8*>(smem + offA[kk][i]);
#pragma unroll
      for (int i = 0; i < 4; ++i) bv[i] = *reinterpret_cast<const bf16x8*>(smem + offB[kk][i]);
#pragma unroll
      for (int mi = 0; mi < 4; ++mi)
#pragma unroll
        for (int ni = 0; ni < 4; ++ni)
          acc[mi][ni] = __builtin_amdgcn_mfma_f32_16x16x32_bf16(av[mi], bv[ni], acc[mi][ni], 0, 0, 0);
    }
  }

  float c0 = 0.f, c1 = 0.f, c2 = 0.f;
  if constexpr (MODE == 2) { c0 = coef[0]; c1 = coef[1]; c2 = coef[2]; }
  const int r0 = tm * 128 + wr * 64 + ((l >> 4) << 2);
  const int cb = tn * 128 + wc * 64 + (l & 15);
#pragma unroll
  for (int mi = 0; mi < 4; ++mi) {
#pragma unroll
    for (int ni = 0; ni < 4; ++ni) {
      const int ccol = cb + ni * 16;
#pragma unroll
      for (int j = 0; j < 4; ++j) {
        const int rrow = r0 + mi * 16 + j;
        const size_t idx = boff + (size_t)rrow * LDW + ccol;
        float v = acc[mi][ni][j];
        if constexpr (MODE == 2) {
          v = c0 * exf[idx] + c1 * (b2f(exh[idx]) + b2f(exl[idx])) + c2 * v;
          of[idx] = v;
        }
        __hip_bfloat16 h = f2b(v);
        __hip_bfloat16 lo = f2b(v - b2f(h));
        oh[idx] = h;
        ol[idx] = lo;
        if constexpr (MODE == 2) {
          const size_t tix = boff + (size_t)ccol * LDW + rrow;
          oth[tix] = h;
          otl[tix] = lo;
        }
      }
    }
  }
}

extern "C" void kernel_launch(void* const* d_in, const int* in_sizes, int n_in,
                              void* d_out, int out_size, void* d_ws, size_t ws_size,
                              hipStream_t stream) {
  (void)in_sizes; (void)n_in; (void)out_size;
  const float* xin = (const float*)d_in[0];
  const float* coef = (const float*)d_in[1];
  float* xout = (float*)d_out;

  // ws need: 8 bf16 buffers x CH x 2MB = 16 MB/batch (+64KB slack)
  int CH = 64;
  while (CH > 1 && ((size_t)CH * 16u * 1024u * 1024u + 65536u) > ws_size) CH >>= 1;

  const size_t nE = (size_t)CH << BATCH_SH;
  __hip_bfloat16* Xh = (__hip_bfloat16*)d_ws;
  __hip_bfloat16* Xl = Xh + nE;
  __hip_bfloat16* XTh = Xl + nE;
  __hip_bfloat16* XTl = XTh + nE;
  __hip_bfloat16* Ah = XTl + nE;
  __hip_bfloat16* Al = Ah + nE;
  __hip_bfloat16* T1h = Al + nE;
  __hip_bfloat16* T1l = T1h + nE;
  float* partials = (float*)(T1l + nE);
  float* scales = partials + (size_t)CH * 64;

  for (int c = 0; c < 64; c += CH) {
    const float* xi = xin + ((size_t)c << BATCH_SH);
    float* X = xout + ((size_t)c << BATCH_SH);  // fp32 X lives in d_out
    k_partial<<<dim3(64, CH), 256, 0, stream>>>(xi, partials);
    k_scale<<<dim3(CH), 64, 0, stream>>>(partials, scales);
    k_scalesplit<<<dim3(16, 16, CH), 256, 0, stream>>>(xi, scales, X, Xh, Xl, XTh, XTl);
    for (int it = 0; it < 5; ++it) {
      // A = X^T X = XT * XT^T :  hi*hi + hi*lo + lo*hi
      k_gemm<0><<<dim3(64, CH), 256, 0, stream>>>(XTh, XTh, XTl, XTh, XTl, XTh,
                                                  Ah, Al, nullptr, nullptr,
                                                  nullptr, nullptr, nullptr, nullptr, nullptr);
      // T1 = X * A (A symmetric -> C = X * A^T = X * A)
      k_gemm<0><<<dim3(64, CH), 256, 0, stream>>>(Xh, Xh, Xl, Ah, Al, Ah,
                                                  T1h, T1l, nullptr, nullptr,
                                                  nullptr, nullptr, nullptr, nullptr, nullptr);
      // T2 = T1 * A ; X <- c0*X + c1*T1 + c2*T2 (in place), emit next-iter splits
      k_gemm<2><<<dim3(64, CH), 256, 0, stream>>>(T1h, T1h, T1l, Ah, Al, Ah,
                                                  Xh, Xl, XTh, XTl,
                                                  X, X, T1h, T1l, coef);
    }
  }
}

// Round 3
// 11535.620 us; speedup vs baseline: 1.0645x; 1.0645x over previous
//
#include <hip/hip_runtime.h>
#include <hip/hip_bf16.h>
#include <stdint.h>

typedef float f32x4 __attribute__((ext_vector_type(4)));
typedef short bf16x8 __attribute__((ext_vector_type(8)));

#define LDW 1024
#define BATCH_SH 20  // 1<<20 elements per 1024x1024 matrix

__device__ __forceinline__ float b2f(__hip_bfloat16 h) { return __bfloat162float(h); }
__device__ __forceinline__ __hip_bfloat16 f2b(float f) { return __float2bfloat16(f); }

// ---------------- Frobenius norm (2-stage) ----------------
__global__ void k_partial(const float* __restrict__ xin, float* __restrict__ partials) {
  const int b = blockIdx.y, ch = blockIdx.x, t = threadIdx.x;
  const size_t base = ((size_t)b << BATCH_SH) + (size_t)ch * 16384;
  float s = 0.f;
#pragma unroll
  for (int i = 0; i < 16; ++i) {
    f32x4 v = *reinterpret_cast<const f32x4*>(xin + base + (size_t)(i * 256 + t) * 4);
    s += v[0] * v[0] + v[1] * v[1] + v[2] * v[2] + v[3] * v[3];
  }
#pragma unroll
  for (int off = 32; off; off >>= 1) s += __shfl_down(s, off);
  __shared__ float red[4];
  if ((t & 63) == 0) red[t >> 6] = s;
  __syncthreads();
  if (t == 0) partials[b * 64 + ch] = red[0] + red[1] + red[2] + red[3];
}

__global__ void k_scale(const float* __restrict__ partials, float* __restrict__ scales) {
  const int b = blockIdx.x, t = threadIdx.x;
  float s = partials[b * 64 + t];
#pragma unroll
  for (int off = 32; off; off >>= 1) s += __shfl_down(s, off);
  if (t == 0) scales[b] = 1.1f / sqrtf(s);
}

// ---------------- scale + split + transpose-split (no fp32 X output) ----------------
__global__ void k_scalesplit(const float* __restrict__ xin, const float* __restrict__ scales,
                             __hip_bfloat16* __restrict__ Xh, __hip_bfloat16* __restrict__ Xl,
                             __hip_bfloat16* __restrict__ XTh, __hip_bfloat16* __restrict__ XTl) {
  __shared__ float tile[64][65];
  const int b = blockIdx.z, tm = blockIdx.y, tn = blockIdx.x;
  const size_t boff = (size_t)b << BATCH_SH;
  const float s = scales[b];
  const int t = threadIdx.x, lr0 = t >> 6, lc = t & 63;
#pragma unroll
  for (int p = 0; p < 16; ++p) {
    const int lr = p * 4 + lr0;
    const size_t idx = boff + (size_t)(tm * 64 + lr) * LDW + tn * 64 + lc;
    const float v = xin[idx] * s;
    __hip_bfloat16 h = f2b(v);
    Xh[idx] = h;
    Xl[idx] = f2b(v - b2f(h));
    tile[lr][lc] = v;
  }
  __syncthreads();
#pragma unroll
  for (int p = 0; p < 16; ++p) {
    const int lr = p * 4 + lr0;
    const float v = tile[lc][lr];
    const size_t idx = boff + (size_t)(tn * 64 + lr) * LDW + tm * 64 + lc;
    __hip_bfloat16 h = f2b(v);
    XTh[idx] = h;
    XTl[idx] = f2b(v - b2f(h));
  }
}

// ---------------- split-bf16 GEMM: C = PA * PB^T over 3 K-segments ----------------
// Register-staged LDS, software-pipelined prefetch, XCD-aware block swizzle.
// MODE 0: oh/ol = hi/lo splits of C
// MODE 2: xn = c0*(e0h+e0l) + c1*(e1h+e1l) + c2*C; oh/ol = splits of xn;
//         oth/otl = transposed splits; if (of) of = xn fp32.

#define LOADREGS(S)                                                                       \
  {                                                                                       \
    const int seg_ = (S) >> 4, k0_ = ((S) & 15) << 6;                                     \
    const __hip_bfloat16* pa_ = seg_ == 0 ? pa0 : seg_ == 1 ? pa1 : pa2;                  \
    const __hip_bfloat16* pb_ = seg_ == 0 ? pb0 : seg_ == 1 ? pb1 : pb2;                  \
    _Pragma("unroll") for (int it_ = 0; it_ < 4; ++it_) {                                 \
      const int r_ = w * 32 + it_ * 8 + srow;                                             \
      va[it_] = *reinterpret_cast<const bf16x8*>(pa_ + boff + (size_t)(rowA + r_) * LDW + \
                                                 k0_ + gl * 8);                           \
      vb[it_] = *reinterpret_cast<const bf16x8*>(pb_ + boff + (size_t)(rowB + r_) * LDW + \
                                                 k0_ + gl * 8);                           \
    }                                                                                     \
  }

template <int MODE>
__global__ __launch_bounds__(256) void k_gemm(
    const __hip_bfloat16* __restrict__ pa0, const __hip_bfloat16* __restrict__ pa1,
    const __hip_bfloat16* __restrict__ pa2, const __hip_bfloat16* __restrict__ pb0,
    const __hip_bfloat16* __restrict__ pb1, const __hip_bfloat16* __restrict__ pb2,
    __hip_bfloat16* __restrict__ oh, __hip_bfloat16* __restrict__ ol,
    __hip_bfloat16* __restrict__ oth, __hip_bfloat16* __restrict__ otl,
    float* __restrict__ of,
    const __hip_bfloat16* __restrict__ e0h, const __hip_bfloat16* __restrict__ e0l,
    const __hip_bfloat16* __restrict__ e1h, const __hip_bfloat16* __restrict__ e1l,
    const float* __restrict__ coef) {
  __shared__ __align__(16) char smem[32768];  // A 16KB + B 16KB, single buffer
  const int tid = threadIdx.x;
  const int w = tid >> 6, l = tid & 63;
  const int wr = w >> 1, wc = w & 1;

  // XCD-aware bijective swizzle: each XCD gets a contiguous chunk of wgids
  // (whole batches) so same-batch panel reuse hits one L2. gridDim.x % 8 == 0.
  const int q = gridDim.x >> 3;
  const int orig = blockIdx.x;
  const int wgid = (orig & 7) * q + (orig >> 3);
  const int bat = wgid >> 6, tile = wgid & 63;
  const size_t boff = (size_t)bat << BATCH_SH;
  const int tm = tile >> 3, tn = tile & 7;
  const int rowA = tm * 128, rowB = tn * 128;
  const int srow = l >> 3, gl = l & 7;

  f32x4 acc[4][4];
#pragma unroll
  for (int i = 0; i < 4; ++i)
#pragma unroll
    for (int j = 0; j < 4; ++j) acc[i][j] = (f32x4){0.f, 0.f, 0.f, 0.f};

  // LDS byte offsets of MFMA fragments (XOR chunk swizzle, matches write side)
  int offA[2][4], offB[2][4];
#pragma unroll
  for (int kk = 0; kk < 2; ++kk) {
#pragma unroll
    for (int i = 0; i < 4; ++i) {
      const int g = kk * 4 + (l >> 4);
      const int rA = wr * 64 + i * 16 + (l & 15);
      offA[kk][i] = rA * 128 + ((g ^ (rA & 7)) << 4);
      const int rB = wc * 64 + i * 16 + (l & 15);
      offB[kk][i] = 16384 + rB * 128 + ((g ^ (rB & 7)) << 4);
    }
  }

  bf16x8 va[4], vb[4];
  LOADREGS(0);

  for (int s = 0; s < 48; ++s) {
    __syncthreads();  // all waves done reading smem (previous step)
#pragma unroll
    for (int it = 0; it < 4; ++it) {
      const int r = w * 32 + it * 8 + srow;
      // chunk gl of row r goes to slot gl ^ (r&7); (r&7) == srow
      *reinterpret_cast<bf16x8*>(smem + r * 128 + ((gl ^ srow) << 4)) = va[it];
      *reinterpret_cast<bf16x8*>(smem + 16384 + r * 128 + ((gl ^ srow) << 4)) = vb[it];
    }
    __syncthreads();  // smem staged
    if (s + 1 < 48) LOADREGS(s + 1);  // prefetch next step; latency hides under MFMA
#pragma unroll
    for (int kk = 0; kk < 2; ++kk) {
      bf16x8 av[4], bv[4];
#pragma unroll
      for (int i = 0; i < 4; ++i) av[i] = *reinterpret_cast<const bf16x8*>(smem + offA[kk][i]);
#pragma unroll
      for (int i = 0; i < 4; ++i) bv[i] = *reinterpret_cast<const bf16x8*>(smem + offB[kk][i]);
#pragma unroll
      for (int mi = 0; mi < 4; ++mi)
#pragma unroll
        for (int ni = 0; ni < 4; ++ni)
          acc[mi][ni] = __builtin_amdgcn_mfma_f32_16x16x32_bf16(av[mi], bv[ni], acc[mi][ni], 0, 0, 0);
    }
  }

  float c0 = 0.f, c1 = 0.f, c2 = 0.f;
  if constexpr (MODE == 2) { c0 = coef[0]; c1 = coef[1]; c2 = coef[2]; }
  const int r0 = tm * 128 + wr * 64 + ((l >> 4) << 2);
  const int cb = tn * 128 + wc * 64 + (l & 15);
#pragma unroll
  for (int mi = 0; mi < 4; ++mi) {
#pragma unroll
    for (int ni = 0; ni < 4; ++ni) {
      const int ccol = cb + ni * 16;
#pragma unroll
      for (int j = 0; j < 4; ++j) {
        const int rrow = r0 + mi * 16 + j;
        const size_t idx = boff + (size_t)rrow * LDW + ccol;
        float v = acc[mi][ni][j];
        if constexpr (MODE == 2) {
          v = c0 * (b2f(e0h[idx]) + b2f(e0l[idx])) +
              c1 * (b2f(e1h[idx]) + b2f(e1l[idx])) + c2 * v;
          if (of) of[idx] = v;
        }
        __hip_bfloat16 h = f2b(v);
        __hip_bfloat16 lo = f2b(v - b2f(h));
        oh[idx] = h;
        ol[idx] = lo;
        if constexpr (MODE == 2) {
          const size_t tix = boff + (size_t)ccol * LDW + rrow;
          oth[tix] = h;
          otl[tix] = lo;
        }
      }
    }
  }
}

extern "C" void kernel_launch(void* const* d_in, const int* in_sizes, int n_in,
                              void* d_out, int out_size, void* d_ws, size_t ws_size,
                              hipStream_t stream) {
  (void)in_sizes; (void)n_in; (void)out_size;
  const float* xin = (const float*)d_in[0];
  const float* coef = (const float*)d_in[1];
  float* xout = (float*)d_out;

  // ws need: 8 bf16 buffers x CH x 2MB = 16 MB/batch (+64KB slack)
  int CH = 64;
  while (CH > 1 && ((size_t)CH * 16u * 1024u * 1024u + 65536u) > ws_size) CH >>= 1;

  const size_t nE = (size_t)CH << BATCH_SH;
  __hip_bfloat16* Xh = (__hip_bfloat16*)d_ws;
  __hip_bfloat16* Xl = Xh + nE;
  __hip_bfloat16* XTh = Xl + nE;
  __hip_bfloat16* XTl = XTh + nE;
  __hip_bfloat16* Ah = XTl + nE;
  __hip_bfloat16* Al = Ah + nE;
  __hip_bfloat16* T1h = Al + nE;
  __hip_bfloat16* T1l = T1h + nE;
  float* partials = (float*)(T1l + nE);
  float* scales = partials + (size_t)CH * 64;

  for (int c = 0; c < 64; c += CH) {
    const float* xi = xin + ((size_t)c << BATCH_SH);
    float* X = xout + ((size_t)c << BATCH_SH);  // final output only
    k_partial<<<dim3(64, CH), 256, 0, stream>>>(xi, partials);
    k_scale<<<dim3(CH), 64, 0, stream>>>(partials, scales);
    k_scalesplit<<<dim3(16, 16, CH), 256, 0, stream>>>(xi, scales, Xh, Xl, XTh, XTl);
    for (int it = 0; it < 5; ++it) {
      // A = X^T X = XT * XT^T :  hi*hi + hi*lo + lo*hi
      k_gemm<0><<<dim3(CH * 64), 256, 0, stream>>>(XTh, XTh, XTl, XTh, XTl, XTh,
                                                   Ah, Al, nullptr, nullptr, nullptr,
                                                   nullptr, nullptr, nullptr, nullptr, nullptr);
      // T1 = X * A  (A symmetric)
      k_gemm<0><<<dim3(CH * 64), 256, 0, stream>>>(Xh, Xh, Xl, Ah, Al, Ah,
                                                   T1h, T1l, nullptr, nullptr, nullptr,
                                                   nullptr, nullptr, nullptr, nullptr, nullptr);
      // T2 = T1 * A ; X <- c0*X + c1*T1 + c2*T2 ; emit next-iter splits (+fp32 on last)
      k_gemm<2><<<dim3(CH * 64), 256, 0, stream>>>(T1h, T1h, T1l, Ah, Al, Ah,
                                                   Xh, Xl, XTh, XTl,
                                                   (it == 4) ? X : nullptr,
                                                   Xh, Xl, T1h, T1l, coef);
    }
  }
}

// Round 4
// 8791.772 us; speedup vs baseline: 1.3967x; 1.3121x over previous
//
#include <hip/hip_runtime.h>
#include <hip/hip_bf16.h>
#include <stdint.h>

typedef float f32x4 __attribute__((ext_vector_type(4)));
typedef short bf16x8 __attribute__((ext_vector_type(8)));

#define LDW 1024
#define BATCH_SH 20  // 1<<20 elements per 1024x1024 matrix

__device__ __forceinline__ float b2f(__hip_bfloat16 h) { return __bfloat162float(h); }
__device__ __forceinline__ __hip_bfloat16 f2b(float f) { return __float2bfloat16(f); }

// ---------------- Frobenius norm (2-stage) ----------------
__global__ void k_partial(const float* __restrict__ xin, float* __restrict__ partials) {
  const int b = blockIdx.y, ch = blockIdx.x, t = threadIdx.x;
  const size_t base = ((size_t)b << BATCH_SH) + (size_t)ch * 16384;
  float s = 0.f;
#pragma unroll
  for (int i = 0; i < 16; ++i) {
    f32x4 v = *reinterpret_cast<const f32x4*>(xin + base + (size_t)(i * 256 + t) * 4);
    s += v[0] * v[0] + v[1] * v[1] + v[2] * v[2] + v[3] * v[3];
  }
#pragma unroll
  for (int off = 32; off; off >>= 1) s += __shfl_down(s, off);
  __shared__ float red[4];
  if ((t & 63) == 0) red[t >> 6] = s;
  __syncthreads();
  if (t == 0) partials[b * 64 + ch] = red[0] + red[1] + red[2] + red[3];
}

__global__ void k_scale(const float* __restrict__ partials, float* __restrict__ scales) {
  const int b = blockIdx.x, t = threadIdx.x;
  float s = partials[b * 64 + t];
#pragma unroll
  for (int off = 32; off; off >>= 1) s += __shfl_down(s, off);
  if (t == 0) scales[b] = 1.1f / sqrtf(s);
}

// ---------------- scale + split + transpose-split ----------------
__global__ void k_scalesplit(const float* __restrict__ xin, const float* __restrict__ scales,
                             __hip_bfloat16* __restrict__ Xh, __hip_bfloat16* __restrict__ Xl,
                             __hip_bfloat16* __restrict__ XTh, __hip_bfloat16* __restrict__ XTl) {
  __shared__ float tile[64][65];
  const int b = blockIdx.z, tm = blockIdx.y, tn = blockIdx.x;
  const size_t boff = (size_t)b << BATCH_SH;
  const float s = scales[b];
  const int t = threadIdx.x, lr0 = t >> 6, lc = t & 63;
#pragma unroll
  for (int p = 0; p < 16; ++p) {
    const int lr = p * 4 + lr0;
    const size_t idx = boff + (size_t)(tm * 64 + lr) * LDW + tn * 64 + lc;
    const float v = xin[idx] * s;
    __hip_bfloat16 h = f2b(v);
    Xh[idx] = h;
    Xl[idx] = f2b(v - b2f(h));
    tile[lr][lc] = v;
  }
  __syncthreads();
#pragma unroll
  for (int p = 0; p < 16; ++p) {
    const int lr = p * 4 + lr0;
    const float v = tile[lc][lr];
    const size_t idx = boff + (size_t)(tn * 64 + lr) * LDW + tm * 64 + lc;
    __hip_bfloat16 h = f2b(v);
    XTh[idx] = h;
    XTl[idx] = f2b(v - b2f(h));
  }
}

// ---------------- split-bf16 GEMM: C = PA * PB^T, 256x256 tile, BK=64 ----------------
// Effective K = 3072 (3 bf16 segments). 512 threads = 8 waves (2M x 4N),
// per-wave output 128x64. Double-buffered 128 KiB LDS, reg-staged with XOR
// chunk swizzle (self-consistent write/read). One raw s_barrier per K-step:
// lgkmcnt(0)+sched_barrier fencing publishes ds_writes without draining vmcnt,
// so global prefetch loads stay in flight across barriers.

// stage regs: sa[4], sb[4]. thread t stages A rows it*64+(t>>3), chunk t&7 (16B).
#define LOADSTG(S)                                                                        \
  {                                                                                       \
    const int seg_ = (S) >> 4, k0_ = ((S) & 15) << 6;                                     \
    const __hip_bfloat16* pa_ = seg_ == 0 ? pa0 : seg_ == 1 ? pa1 : pa2;                  \
    const __hip_bfloat16* pb_ = seg_ == 0 ? pb0 : seg_ == 1 ? pb1 : pb2;                  \
    _Pragma("unroll") for (int it_ = 0; it_ < 4; ++it_) {                                 \
      const int r_ = it_ * 64 + srow;                                                     \
      sa[it_] = *reinterpret_cast<const bf16x8*>(pa_ + boff + (size_t)(rowA + r_) * LDW + \
                                                 k0_ + chnk * 8);                         \
      sb[it_] = *reinterpret_cast<const bf16x8*>(pb_ + boff + (size_t)(rowB + r_) * LDW + \
                                                 k0_ + chnk * 8);                         \
    }                                                                                     \
  }

#define DSWRITE(DB)                                                                       \
  {                                                                                       \
    char* wb_ = smem + (DB) * 65536;                                                      \
    _Pragma("unroll") for (int it_ = 0; it_ < 4; ++it_) {                                 \
      const int r_ = it_ * 64 + srow;                                                     \
      const int sl_ = (chnk ^ (r_ & 7)) << 4;                                             \
      *reinterpret_cast<bf16x8*>(wb_ + r_ * 128 + sl_) = sa[it_];                         \
      *reinterpret_cast<bf16x8*>(wb_ + 32768 + r_ * 128 + sl_) = sb[it_];                 \
    }                                                                                     \
  }

#define MFMA_PHASE(KK, BASE)                                                              \
  {                                                                                       \
    bf16x8 av[8], bv[4];                                                                  \
    _Pragma("unroll") for (int mi_ = 0; mi_ < 8; ++mi_)                                   \
        av[mi_] = *reinterpret_cast<const bf16x8*>(smem + (BASE) + offA[KK][mi_]);        \
    _Pragma("unroll") for (int ni_ = 0; ni_ < 4; ++ni_)                                   \
        bv[ni_] = *reinterpret_cast<const bf16x8*>(smem + (BASE) + offB[KK][ni_]);        \
    __builtin_amdgcn_s_setprio(1);                                                        \
    _Pragma("unroll") for (int mi_ = 0; mi_ < 8; ++mi_)                                   \
        _Pragma("unroll") for (int ni_ = 0; ni_ < 4; ++ni_)                               \
            acc[mi_][ni_] = __builtin_amdgcn_mfma_f32_16x16x32_bf16(                      \
                av[mi_], bv[ni_], acc[mi_][ni_], 0, 0, 0);                                \
    __builtin_amdgcn_s_setprio(0);                                                        \
  }

template <int MODE>
__global__ __launch_bounds__(512, 2) void k_gemm(
    const __hip_bfloat16* __restrict__ pa0, const __hip_bfloat16* __restrict__ pa1,
    const __hip_bfloat16* __restrict__ pa2, const __hip_bfloat16* __restrict__ pb0,
    const __hip_bfloat16* __restrict__ pb1, const __hip_bfloat16* __restrict__ pb2,
    __hip_bfloat16* __restrict__ oh, __hip_bfloat16* __restrict__ ol,
    __hip_bfloat16* __restrict__ oth, __hip_bfloat16* __restrict__ otl,
    float* __restrict__ of,
    const __hip_bfloat16* __restrict__ e0h, const __hip_bfloat16* __restrict__ e0l,
    const __hip_bfloat16* __restrict__ e1h, const __hip_bfloat16* __restrict__ e1l,
    const float* __restrict__ coef) {
  __shared__ __align__(16) char smem[131072];  // 2 bufs x (A 32KB + B 32KB)
  const int t = threadIdx.x;
  const int w = t >> 6, l = t & 63;
  const int wr = w >> 2, wc = w & 3;  // 2M x 4N wave grid
  const int srow = t >> 3, chnk = t & 7;  // staging map: 64 rows/it, 8 chunks

  // XCD-aware bijective swizzle (gridDim.x % 8 == 0): contiguous wgid chunk per XCD.
  const int q = gridDim.x >> 3;
  const int orig = blockIdx.x;
  const int wgid = (orig & 7) * q + (orig >> 3);
  const int bat = wgid >> 4, tile = wgid & 15;
  const size_t boff = (size_t)bat << BATCH_SH;
  const int tm = tile >> 2, tn = tile & 3;
  const int rowA = tm * 256, rowB = tn * 256;

  f32x4 acc[8][4];
#pragma unroll
  for (int i = 0; i < 8; ++i)
#pragma unroll
    for (int j = 0; j < 4; ++j) acc[i][j] = (f32x4){0.f, 0.f, 0.f, 0.f};

  // MFMA fragment LDS byte offsets (within a buffer), XOR chunk swizzle
  int offA[2][8], offB[2][4];
#pragma unroll
  for (int kk = 0; kk < 2; ++kk) {
    const int g = kk * 4 + (l >> 4);
#pragma unroll
    for (int mi = 0; mi < 8; ++mi) {
      const int rA = wr * 128 + mi * 16 + (l & 15);
      offA[kk][mi] = rA * 128 + ((g ^ (rA & 7)) << 4);
    }
#pragma unroll
    for (int ni = 0; ni < 4; ++ni) {
      const int rB = wc * 64 + ni * 16 + (l & 15);
      offB[kk][ni] = 32768 + rB * 128 + ((g ^ (rB & 7)) << 4);
    }
  }

  bf16x8 sa[4], sb[4];
  // prologue: stage tile 0 into buf0, prefetch tile 1 into regs
  LOADSTG(0);
  DSWRITE(0);
  LOADSTG(1);
  asm volatile("s_waitcnt lgkmcnt(0)" ::: "memory");
  __builtin_amdgcn_sched_barrier(0);
  __builtin_amdgcn_s_barrier();
  __builtin_amdgcn_sched_barrier(0);

  for (int s = 0; s < 48; ++s) {
    const int base = (s & 1) * 65536;
    MFMA_PHASE(0, base);                 // kk=0 on current tile
    if (s + 1 < 48) DSWRITE((s & 1) ^ 1);  // publish tile s+1 (regs from last step)
    if (s + 2 < 48) LOADSTG(s + 2);        // prefetch tile s+2 (stays in flight)
    MFMA_PHASE(1, base);                 // kk=1 on current tile
    asm volatile("s_waitcnt lgkmcnt(0)" ::: "memory");  // ds_writes retired, reads done
    __builtin_amdgcn_sched_barrier(0);
    __builtin_amdgcn_s_barrier();        // raw barrier: vmcnt NOT drained
    __builtin_amdgcn_sched_barrier(0);
  }

  float c0 = 0.f, c1 = 0.f, c2 = 0.f;
  if constexpr (MODE == 2) { c0 = coef[0]; c1 = coef[1]; c2 = coef[2]; }
  const int r0 = tm * 256 + wr * 128 + ((l >> 4) << 2);
  const int cb = tn * 256 + wc * 64 + (l & 15);
#pragma unroll
  for (int mi = 0; mi < 8; ++mi) {
#pragma unroll
    for (int ni = 0; ni < 4; ++ni) {
      const int ccol = cb + ni * 16;
#pragma unroll
      for (int j = 0; j < 4; ++j) {
        const int rrow = r0 + mi * 16 + j;
        const size_t idx = boff + (size_t)rrow * LDW + ccol;
        float v = acc[mi][ni][j];
        if constexpr (MODE == 2) {
          v = c0 * (b2f(e0h[idx]) + b2f(e0l[idx])) +
              c1 * (b2f(e1h[idx]) + b2f(e1l[idx])) + c2 * v;
          if (of) of[idx] = v;
        }
        __hip_bfloat16 h = f2b(v);
        __hip_bfloat16 lo = f2b(v - b2f(h));
        oh[idx] = h;
        ol[idx] = lo;
        if constexpr (MODE == 2) {
          const size_t tix = boff + (size_t)ccol * LDW + rrow;
          oth[tix] = h;
          otl[tix] = lo;
        }
      }
    }
  }
}

extern "C" void kernel_launch(void* const* d_in, const int* in_sizes, int n_in,
                              void* d_out, int out_size, void* d_ws, size_t ws_size,
                              hipStream_t stream) {
  (void)in_sizes; (void)n_in; (void)out_size;
  const float* xin = (const float*)d_in[0];
  const float* coef = (const float*)d_in[1];
  float* xout = (float*)d_out;

  // ws need: 8 bf16 buffers x CH x 2MB = 16 MB/batch (+64KB slack)
  int CH = 64;
  while (CH > 1 && ((size_t)CH * 16u * 1024u * 1024u + 65536u) > ws_size) CH >>= 1;

  const size_t nE = (size_t)CH << BATCH_SH;
  __hip_bfloat16* Xh = (__hip_bfloat16*)d_ws;
  __hip_bfloat16* Xl = Xh + nE;
  __hip_bfloat16* XTh = Xl + nE;
  __hip_bfloat16* XTl = XTh + nE;
  __hip_bfloat16* Ah = XTl + nE;
  __hip_bfloat16* Al = Ah + nE;
  __hip_bfloat16* T1h = Al + nE;
  __hip_bfloat16* T1l = T1h + nE;
  float* partials = (float*)(T1l + nE);
  float* scales = partials + (size_t)CH * 64;

  for (int c = 0; c < 64; c += CH) {
    const float* xi = xin + ((size_t)c << BATCH_SH);
    float* X = xout + ((size_t)c << BATCH_SH);  // final output only
    k_partial<<<dim3(64, CH), 256, 0, stream>>>(xi, partials);
    k_scale<<<dim3(CH), 64, 0, stream>>>(partials, scales);
    k_scalesplit<<<dim3(16, 16, CH), 256, 0, stream>>>(xi, scales, Xh, Xl, XTh, XTl);
    for (int it = 0; it < 5; ++it) {
      // A = X^T X = XT * XT^T :  hi*hi + hi*lo + lo*hi
      k_gemm<0><<<dim3(CH * 16), 512, 0, stream>>>(XTh, XTh, XTl, XTh, XTl, XTh,
                                                   Ah, Al, nullptr, nullptr, nullptr,
                                                   nullptr, nullptr, nullptr, nullptr, nullptr);
      // T1 = X * A  (A symmetric)
      k_gemm<0><<<dim3(CH * 16), 512, 0, stream>>>(Xh, Xh, Xl, Ah, Al, Ah,
                                                   T1h, T1l, nullptr, nullptr, nullptr,
                                                   nullptr, nullptr, nullptr, nullptr, nullptr);
      // T2 = T1 * A ; X <- c0*X + c1*T1 + c2*T2 ; emit next-iter splits (+fp32 on last)
      k_gemm<2><<<dim3(CH * 16), 512, 0, stream>>>(T1h, T1h, T1l, Ah, Al, Ah,
                                                   Xh, Xl, XTh, XTl,
                                                   (it == 4) ? X : nullptr,
                                                   Xh, Xl, T1h, T1l, coef);
    }
  }
}

// Round 5
// 7783.730 us; speedup vs baseline: 1.5776x; 1.1295x over previous
//
#include <hip/hip_runtime.h>
#include <hip/hip_bf16.h>
#include <stdint.h>

typedef float f32x4 __attribute__((ext_vector_type(4)));
typedef short bf16x8 __attribute__((ext_vector_type(8)));

#define LDW 1024
#define BATCH_SH 20  // 1<<20 elements per 1024x1024 matrix

__device__ __forceinline__ float b2f(__hip_bfloat16 h) { return __bfloat162float(h); }
__device__ __forceinline__ __hip_bfloat16 f2b(float f) { return __float2bfloat16(f); }

// ---------------- Frobenius norm (2-stage) ----------------
__global__ void k_partial(const float* __restrict__ xin, float* __restrict__ partials) {
  const int b = blockIdx.y, ch = blockIdx.x, t = threadIdx.x;
  const size_t base = ((size_t)b << BATCH_SH) + (size_t)ch * 16384;
  float s = 0.f;
#pragma unroll
  for (int i = 0; i < 16; ++i) {
    f32x4 v = *reinterpret_cast<const f32x4*>(xin + base + (size_t)(i * 256 + t) * 4);
    s += v[0] * v[0] + v[1] * v[1] + v[2] * v[2] + v[3] * v[3];
  }
#pragma unroll
  for (int off = 32; off; off >>= 1) s += __shfl_down(s, off);
  __shared__ float red[4];
  if ((t & 63) == 0) red[t >> 6] = s;
  __syncthreads();
  if (t == 0) partials[b * 64 + ch] = red[0] + red[1] + red[2] + red[3];
}

__global__ void k_scale(const float* __restrict__ partials, float* __restrict__ scales) {
  const int b = blockIdx.x, t = threadIdx.x;
  float s = partials[b * 64 + t];
#pragma unroll
  for (int off = 32; off; off >>= 1) s += __shfl_down(s, off);
  if (t == 0) scales[b] = 1.1f / sqrtf(s);
}

// ---------------- scale + split + transpose-split ----------------
__global__ void k_scalesplit(const float* __restrict__ xin, const float* __restrict__ scales,
                             __hip_bfloat16* __restrict__ Xh, __hip_bfloat16* __restrict__ Xl,
                             __hip_bfloat16* __restrict__ XTh, __hip_bfloat16* __restrict__ XTl) {
  __shared__ float tile[64][65];
  const int b = blockIdx.z, tm = blockIdx.y, tn = blockIdx.x;
  const size_t boff = (size_t)b << BATCH_SH;
  const float s = scales[b];
  const int t = threadIdx.x, lr0 = t >> 6, lc = t & 63;
#pragma unroll
  for (int p = 0; p < 16; ++p) {
    const int lr = p * 4 + lr0;
    const size_t idx = boff + (size_t)(tm * 64 + lr) * LDW + tn * 64 + lc;
    const float v = xin[idx] * s;
    __hip_bfloat16 h = f2b(v);
    Xh[idx] = h;
    Xl[idx] = f2b(v - b2f(h));
    tile[lr][lc] = v;
  }
  __syncthreads();
#pragma unroll
  for (int p = 0; p < 16; ++p) {
    const int lr = p * 4 + lr0;
    const float v = tile[lc][lr];
    const size_t idx = boff + (size_t)(tn * 64 + lr) * LDW + tm * 64 + lc;
    __hip_bfloat16 h = f2b(v);
    XTh[idx] = h;
    XTl[idx] = f2b(v - b2f(h));
  }
}

// ---------------- split-bf16 GEMM: C = PA * PB^T, 256x256 tile, BK=64 ----------------
// Effective K = 3072 (3 bf16 segments). 512 threads = 8 waves (2M x 4N).
// Schedule identical to round 4 (1 raw barrier/K-step, vmcnt never drained).
// MODE 1 (SYM):  C symmetric; 10 upper tiles; write splits at (i,j) and (j,i).
// MODE 2 (POLY): v = c2*C + c1*A + c0*I (A via eh/el); symmetric writes like MODE 1.
// MODE 3 (XUP):  v = C; if(oh) write splits + transposed splits; if(of) write fp32.

#define LOADSTG(S)                                                                        \
  {                                                                                       \
    const int seg_ = (S) >> 4, k0_ = ((S) & 15) << 6;                                     \
    const __hip_bfloat16* pa_ = seg_ == 0 ? pa0 : seg_ == 1 ? pa1 : pa2;                  \
    const __hip_bfloat16* pb_ = seg_ == 0 ? pb0 : seg_ == 1 ? pb1 : pb2;                  \
    _Pragma("unroll") for (int it_ = 0; it_ < 4; ++it_) {                                 \
      const int r_ = it_ * 64 + srow;                                                     \
      sa[it_] = *reinterpret_cast<const bf16x8*>(pa_ + boff + (size_t)(rowA + r_) * LDW + \
                                                 k0_ + chnk * 8);                         \
      sb[it_] = *reinterpret_cast<const bf16x8*>(pb_ + boff + (size_t)(rowB + r_) * LDW + \
                                                 k0_ + chnk * 8);                         \
    }                                                                                     \
  }

#define DSWRITE(DB)                                                                       \
  {                                                                                       \
    char* wb_ = smem + (DB) * 65536;                                                      \
    _Pragma("unroll") for (int it_ = 0; it_ < 4; ++it_) {                                 \
      const int r_ = it_ * 64 + srow;                                                     \
      const int sl_ = (chnk ^ (r_ & 7)) << 4;                                             \
      *reinterpret_cast<bf16x8*>(wb_ + r_ * 128 + sl_) = sa[it_];                         \
      *reinterpret_cast<bf16x8*>(wb_ + 32768 + r_ * 128 + sl_) = sb[it_];                 \
    }                                                                                     \
  }

#define MFMA_PHASE(KK, BASE)                                                              \
  {                                                                                       \
    bf16x8 av[8], bv[4];                                                                  \
    _Pragma("unroll") for (int mi_ = 0; mi_ < 8; ++mi_)                                   \
        av[mi_] = *reinterpret_cast<const bf16x8*>(smem + (BASE) + offA[KK][mi_]);        \
    _Pragma("unroll") for (int ni_ = 0; ni_ < 4; ++ni_)                                   \
        bv[ni_] = *reinterpret_cast<const bf16x8*>(smem + (BASE) + offB[KK][ni_]);        \
    __builtin_amdgcn_s_setprio(1);                                                        \
    _Pragma("unroll") for (int mi_ = 0; mi_ < 8; ++mi_)                                   \
        _Pragma("unroll") for (int ni_ = 0; ni_ < 4; ++ni_)                               \
            acc[mi_][ni_] = __builtin_amdgcn_mfma_f32_16x16x32_bf16(                      \
                av[mi_], bv[ni_], acc[mi_][ni_], 0, 0, 0);                                \
    __builtin_amdgcn_s_setprio(0);                                                        \
  }

template <int MODE>
__global__ __launch_bounds__(512, 2) void k_gemm(
    const __hip_bfloat16* __restrict__ pa0, const __hip_bfloat16* __restrict__ pa1,
    const __hip_bfloat16* __restrict__ pa2, const __hip_bfloat16* __restrict__ pb0,
    const __hip_bfloat16* __restrict__ pb1, const __hip_bfloat16* __restrict__ pb2,
    __hip_bfloat16* oh, __hip_bfloat16* ol,
    __hip_bfloat16* oth, __hip_bfloat16* otl,
    float* __restrict__ of,
    const __hip_bfloat16* __restrict__ eh, const __hip_bfloat16* __restrict__ el,
    const float* __restrict__ coef) {
  __shared__ __align__(16) char smem[131072];  // 2 bufs x (A 32KB + B 32KB)
  const int t = threadIdx.x;
  const int w = t >> 6, l = t & 63;
  const int wr = w >> 2, wc = w & 3;       // 2M x 4N wave grid
  const int srow = t >> 3, chnk = t & 7;   // staging map: 64 rows/it, 8 chunks

  // Fully-bijective XCD-aware swizzle (m204): works for any gridDim.x.
  const int nwg = gridDim.x, q = nwg >> 3, r8 = nwg & 7;
  const int xcd = blockIdx.x & 7, o = blockIdx.x >> 3;
  const int wgid = (xcd < r8 ? xcd * (q + 1) : r8 * (q + 1) + (xcd - r8) * q) + o;

  int bat, tm, tn;
  if constexpr (MODE == 3) {
    bat = wgid >> 4;
    const int tile = wgid & 15;
    tm = tile >> 2; tn = tile & 3;
  } else {
    bat = (int)((unsigned)wgid / 10u);
    const int tile = wgid - bat * 10;
    tm = (tile < 4) ? 0 : (tile < 7) ? 1 : (tile < 9) ? 2 : 3;
    tn = (tile < 4) ? tile : (tile < 7) ? (tile - 3) : (tile < 9) ? (tile - 5) : 3;
  }
  const size_t boff = (size_t)bat << BATCH_SH;
  const int rowA = tm * 256, rowB = tn * 256;

  f32x4 acc[8][4];
#pragma unroll
  for (int i = 0; i < 8; ++i)
#pragma unroll
    for (int j = 0; j < 4; ++j) acc[i][j] = (f32x4){0.f, 0.f, 0.f, 0.f};

  // MFMA fragment LDS byte offsets (within a buffer), XOR chunk swizzle
  int offA[2][8], offB[2][4];
#pragma unroll
  for (int kk = 0; kk < 2; ++kk) {
    const int g = kk * 4 + (l >> 4);
#pragma unroll
    for (int mi = 0; mi < 8; ++mi) {
      const int rA = wr * 128 + mi * 16 + (l & 15);
      offA[kk][mi] = rA * 128 + ((g ^ (rA & 7)) << 4);
    }
#pragma unroll
    for (int ni = 0; ni < 4; ++ni) {
      const int rB = wc * 64 + ni * 16 + (l & 15);
      offB[kk][ni] = 32768 + rB * 128 + ((g ^ (rB & 7)) << 4);
    }
  }

  bf16x8 sa[4], sb[4];
  // prologue: stage tile 0 into buf0, prefetch tile 1 into regs
  LOADSTG(0);
  DSWRITE(0);
  LOADSTG(1);
  asm volatile("s_waitcnt lgkmcnt(0)" ::: "memory");
  __builtin_amdgcn_sched_barrier(0);
  __builtin_amdgcn_s_barrier();
  __builtin_amdgcn_sched_barrier(0);

  for (int s = 0; s < 48; ++s) {
    const int base = (s & 1) * 65536;
    MFMA_PHASE(0, base);                   // kk=0 on current tile
    if (s + 1 < 48) DSWRITE((s & 1) ^ 1);  // publish tile s+1 (regs from last step)
    if (s + 2 < 48) LOADSTG(s + 2);        // prefetch tile s+2 (stays in flight)
    MFMA_PHASE(1, base);                   // kk=1 on current tile
    asm volatile("s_waitcnt lgkmcnt(0)" ::: "memory");  // ds ops retired
    __builtin_amdgcn_sched_barrier(0);
    __builtin_amdgcn_s_barrier();          // raw barrier: vmcnt NOT drained
    __builtin_amdgcn_sched_barrier(0);
  }

  float c0 = 0.f, c1 = 0.f, c2 = 0.f;
  if constexpr (MODE == 2) { c0 = coef[0]; c1 = coef[1]; c2 = coef[2]; }
  const int r0 = tm * 256 + wr * 128 + ((l >> 4) << 2);
  const int cb = tn * 256 + wc * 64 + (l & 15);
#pragma unroll
  for (int mi = 0; mi < 8; ++mi) {
#pragma unroll
    for (int ni = 0; ni < 4; ++ni) {
      const int ccol = cb + ni * 16;
#pragma unroll
      for (int j = 0; j < 4; ++j) {
        const int rrow = r0 + mi * 16 + j;
        const size_t idx = boff + (size_t)rrow * LDW + ccol;
        const size_t tix = boff + (size_t)ccol * LDW + rrow;
        float v = acc[mi][ni][j];
        if constexpr (MODE == 2)
          v = c2 * v + c1 * (b2f(eh[idx]) + b2f(el[idx])) + (rrow == ccol ? c0 : 0.f);
        __hip_bfloat16 h = f2b(v);
        __hip_bfloat16 lo = f2b(v - b2f(h));
        if constexpr (MODE == 3) {
          if (oh) {
            oh[idx] = h; ol[idx] = lo;
            oth[tix] = h; otl[tix] = lo;
          }
          if (of) of[idx] = v;
        } else {
          oh[idx] = h; ol[idx] = lo;
          if (tm != tn) { oth[tix] = h; otl[tix] = lo; }
        }
      }
    }
  }
}

extern "C" void kernel_launch(void* const* d_in, const int* in_sizes, int n_in,
                              void* d_out, int out_size, void* d_ws, size_t ws_size,
                              hipStream_t stream) {
  (void)in_sizes; (void)n_in; (void)out_size;
  const float* xin = (const float*)d_in[0];
  const float* coef = (const float*)d_in[1];
  float* xout = (float*)d_out;

  // ws need: 8 bf16 buffers (4 pairs) x CH x 2MB = 16 MB/batch (+64KB slack)
  int CH = 64;
  while (CH > 1 && ((size_t)CH * 16u * 1024u * 1024u + 65536u) > ws_size) CH >>= 1;

  const size_t nE = (size_t)CH << BATCH_SH;
  __hip_bfloat16* P0h = (__hip_bfloat16*)d_ws;
  __hip_bfloat16* P0l = P0h + nE;
  __hip_bfloat16* P1h = P0l + nE;
  __hip_bfloat16* P1l = P1h + nE;
  __hip_bfloat16* P2h = P1l + nE;
  __hip_bfloat16* P2l = P2h + nE;
  __hip_bfloat16* XTh = P2l + nE;
  __hip_bfloat16* XTl = XTh + nE;
  float* partials = (float*)(XTl + nE);
  float* scales = partials + (size_t)CH * 64;

  for (int c = 0; c < 64; c += CH) {
    const float* xi = xin + ((size_t)c << BATCH_SH);
    float* X = xout + ((size_t)c << BATCH_SH);  // final fp32 output only
    k_partial<<<dim3(64, CH), 256, 0, stream>>>(xi, partials);
    k_scale<<<dim3(CH), 64, 0, stream>>>(partials, scales);
    k_scalesplit<<<dim3(16, 16, CH), 256, 0, stream>>>(xi, scales, P0h, P0l, XTh, XTl);

    // rotating pairs: X, A, B  (X_next reuses the dead A pair each iteration)
    __hip_bfloat16 *Xh = P0h, *Xl = P0l, *Ah = P1h, *Al = P1l, *Bh = P2h, *Bl = P2l;
    for (int it = 0; it < 5; ++it) {
      // A = XT * XT^T (symmetric, 10 upper tiles): hi*hi + hi*lo + lo*hi
      k_gemm<1><<<dim3(CH * 10), 512, 0, stream>>>(XTh, XTh, XTl, XTh, XTl, XTh,
                                                   Ah, Al, Ah, Al, nullptr,
                                                   nullptr, nullptr, nullptr);
      // B = c2*A^2 + c1*A + c0*I (symmetric, 10 upper tiles)
      k_gemm<2><<<dim3(CH * 10), 512, 0, stream>>>(Ah, Ah, Al, Ah, Al, Ah,
                                                   Bh, Bl, Bh, Bl, nullptr,
                                                   Ah, Al, coef);
      // X_next = X * B^T (B symmetric); splits -> dead A pair; XT splits in place
      k_gemm<3><<<dim3(CH * 16), 512, 0, stream>>>(Xh, Xh, Xl, Bh, Bl, Bh,
                                                   (it < 4) ? Ah : nullptr,
                                                   (it < 4) ? Al : nullptr,
                                                   XTh, XTl,
                                                   (it == 4) ? X : nullptr,
                                                   nullptr, nullptr, nullptr);
      // rotate (X, A, B) <- (A, B, X)
      __hip_bfloat16 *th = Xh, *tl = Xl;
      Xh = Ah; Xl = Al;
      Ah = Bh; Al = Bl;
      Bh = th; Bl = tl;
    }
  }
}